// Round 2
// baseline (628.937 us; speedup 1.0000x reference)
//
#include <hip/hip_runtime.h>
#include <hip/hip_bf16.h>

// EConv via premultiply-on-scatter binning + pure-streaming gather.
//
// R6 post-mortem: 4x MLP in gather was neutral-to-negative -> gather is not
// latency-bound; it is bound by RANDOM 256B edge_attr reads (bucket-permuted
// edge order kills DRAM page locality, ~2 TB/s effective).
// R7: move the multiply into the binning pass. place streams edge_attr
// SEQUENTIALLY (full BW), reads x[src] from LLC, computes msg = ea * x[src],
// and scatter-writes the 256B msg row into the dst bucket (scattered writes
// reorder in the MC write queue -> much cheaper than scattered reads).
// gather is then indirection-free: per node, sum deg contiguous 256B rows.
// Pipeline: memset(cnt+ovf) -> place_mul -> gather -> fixup(overflow, ~0).

#define CAP 36       // bucket slots/node. Poisson(10): P(deg>36) ~ 3e-11/node.
#define OVF_MAX 4096 // overflow edge list (correctness backstop, ~always 0)

typedef float vfloat4 __attribute__((ext_vector_type(4)));

// Pass 1: bin + premultiply. Wave = 16 edges x 4-lane groups; lane owns 16
// contiguous floats (4x float4). edge_attr read is fully coalesced/streaming
// (wave covers 16 consecutive 256B rows); x[src] is a random 64B-granule
// read served by L2/LLC; msg store is a scattered-but-aligned 256B row.
__global__ void place_mul_kernel(const float* __restrict__ x,
                                 const int* __restrict__ edge_index,
                                 const float* __restrict__ edge_attr,
                                 int* __restrict__ cnt,
                                 float* __restrict__ msg,
                                 int* __restrict__ ovf_cnt,
                                 int* __restrict__ ovf,
                                 int E) {
    const int lane = threadIdx.x & 63;
    const int wave = threadIdx.x >> 6;
    const int g = lane >> 2;          // edge slot within wave (0..15)
    const int c = (lane & 3) << 4;    // feature chunk start (0/16/32/48)
    const int e = (blockIdx.x * (blockDim.x >> 6) + wave) * 16 + g;
    if (e >= E) return;               // whole 4-lane group exits together

    const int dst = edge_index[e];
    const int src = edge_index[E + e];
    int p = 0;
    if ((lane & 3) == 0) p = atomicAdd(&cnt[dst], 1);
    p = __shfl(p, 0, 4);              // broadcast within the 4-lane group

    if (p < CAP) {
        const float* ea = edge_attr + (size_t)e * 64 + c;
        const float* xp = x + (size_t)src * 64 + c;
        float* mp = msg + ((size_t)dst * CAP + (size_t)p) * 64 + c;
        vfloat4 e0 = __builtin_nontemporal_load((const vfloat4*)(ea + 0));
        vfloat4 e1 = __builtin_nontemporal_load((const vfloat4*)(ea + 4));
        vfloat4 e2 = __builtin_nontemporal_load((const vfloat4*)(ea + 8));
        vfloat4 e3 = __builtin_nontemporal_load((const vfloat4*)(ea + 12));
        vfloat4 x0 = *(const vfloat4*)(xp + 0);
        vfloat4 x1 = *(const vfloat4*)(xp + 4);
        vfloat4 x2 = *(const vfloat4*)(xp + 8);
        vfloat4 x3 = *(const vfloat4*)(xp + 12);
        __builtin_nontemporal_store(e0 * x0, (vfloat4*)(mp + 0));
        __builtin_nontemporal_store(e1 * x1, (vfloat4*)(mp + 4));
        __builtin_nontemporal_store(e2 * x2, (vfloat4*)(mp + 8));
        __builtin_nontemporal_store(e3 * x3, (vfloat4*)(mp + 12));
    } else if ((lane & 3) == 0) {
        int o = atomicAdd(ovf_cnt, 1);
        if (o < OVF_MAX) ovf[o] = e;
    }
}

// Pass 2: per-node sum of deg contiguous 256B msg rows. One wave per node,
// 4 sixteen-lane groups each own one row slot; lane owns float4 (lane&15)*4.
// No indirection -> addresses are affine, loads stream at full BW.
// Cross-group reduce via shfl_xor(16/32); group 0 stores.
__global__ void gather_kernel(const int* __restrict__ cnt,
                              const float* __restrict__ msg,
                              float* __restrict__ out, int N) {
    const int lane = threadIdx.x & 63;
    const int n = blockIdx.x * (blockDim.x >> 6) + (threadIdx.x >> 6);
    if (n >= N) return;
    const int g = lane >> 4;          // row slot within wave (0..3)
    const int c = (lane & 15) << 2;   // float4 chunk start
    int deg = cnt[n];
    if (deg > CAP) deg = CAP;
    const float* mb = msg + (size_t)n * CAP * 64;
    vfloat4 acc = {0.f, 0.f, 0.f, 0.f};
    int p = g;
    for (; p + 4 < deg; p += 8) {     // unroll 2: both loads independent
        vfloat4 a = __builtin_nontemporal_load((const vfloat4*)(mb + (size_t)p * 64 + c));
        vfloat4 b = __builtin_nontemporal_load((const vfloat4*)(mb + (size_t)(p + 4) * 64 + c));
        acc += a;
        acc += b;
    }
    if (p < deg)
        acc += __builtin_nontemporal_load((const vfloat4*)(mb + (size_t)p * 64 + c));
    acc.x += __shfl_xor(acc.x, 16, 64);
    acc.y += __shfl_xor(acc.y, 16, 64);
    acc.z += __shfl_xor(acc.z, 16, 64);
    acc.w += __shfl_xor(acc.w, 16, 64);
    acc.x += __shfl_xor(acc.x, 32, 64);
    acc.y += __shfl_xor(acc.y, 32, 64);
    acc.z += __shfl_xor(acc.z, 32, 64);
    acc.w += __shfl_xor(acc.w, 32, 64);
    if (g == 0) __builtin_nontemporal_store(acc, (vfloat4*)(out + (size_t)n * 64 + c));
}

// Pass 3: correctness backstop for bucket overflow (expected count: 0).
// One wave; lane owns one feature; atomicAdd into out after gather wrote it.
__global__ void fixup_kernel(const float* __restrict__ x,
                             const float* __restrict__ edge_attr,
                             const int* __restrict__ edge_index,
                             float* __restrict__ out,
                             const int* __restrict__ ovf_cnt,
                             const int* __restrict__ ovf, int E) {
    int cnum = *ovf_cnt;
    if (cnum > OVF_MAX) cnum = OVF_MAX;
    const int lane = threadIdx.x;
    for (int i = 0; i < cnum; i++) {
        int e = ovf[i];
        int dst = edge_index[e], src = edge_index[E + e];
        atomicAdd(&out[(size_t)dst * 64 + lane],
                  x[(size_t)src * 64 + lane] * edge_attr[(size_t)e * 64 + lane]);
    }
}

extern "C" void kernel_launch(void* const* d_in, const int* in_sizes, int n_in,
                              void* d_out, int out_size, void* d_ws, size_t ws_size,
                              hipStream_t stream) {
    const float* x          = (const float*)d_in[0];
    const int*   edge_index = (const int*)d_in[1];
    const float* edge_attr  = (const float*)d_in[2];
    float*       out        = (float*)d_out;

    const int E = in_sizes[1] / 2;   // edge_index is [2, E]
    const int N = out_size / 64;     // d = 64

    // Workspace: msg[N*CAP*64 floats] (~922 MB), then cnt[N], ovf_cnt, ovf.
    char* w = (char*)d_ws;
    float* msg = (float*)w;
    size_t msg_bytes = (size_t)N * CAP * 64 * sizeof(float);
    int* cnt = (int*)(w + msg_bytes);
    int* ovf_cnt = cnt + N;
    int* ovf = ovf_cnt + 1;

    hipMemsetAsync(cnt, 0, (size_t)(N + 1 + OVF_MAX) * sizeof(int), stream);

    const int block = 256;
    // place: 4 waves/block x 16 edges/wave = 64 edges per block
    const int place_grid = (E + 63) / 64;
    place_mul_kernel<<<place_grid, block, 0, stream>>>(x, edge_index, edge_attr,
                                                       cnt, msg, ovf_cnt, ovf, E);

    const int nodes_per_block = block / 64;  // 4 nodes per block
    gather_kernel<<<(N + nodes_per_block - 1) / nodes_per_block, block, 0, stream>>>(
        cnt, msg, out, N);

    fixup_kernel<<<1, 64, 0, stream>>>(x, edge_attr, edge_index, out, ovf_cnt, ovf, E);
}

// Round 3
// 507.065 us; speedup vs baseline: 1.2403x; 1.2403x over previous
//
#include <hip/hip_runtime.h>
#include <hip/hip_bf16.h>

// EConv via direct scatter-atomic: NO data permutation at all.
//
// R7 post-mortem: scattered 256B row WRITES are even worse than scattered
// reads (WRITE_SIZE 462MB vs 256MB written -> partial-line amplification;
// 2.5 TB/s). Every binning variant physically permutes the 256MB edge_attr
// stream and pays ~230-300us. R8 kills the permutation: edges processed in
// NATURAL order (edge_attr streams at full BW), msg = ea * x[src] with x
// served from L2/LLC, and one wave-coalesced 256B atomicAdd per edge into
// out[dst]. out (25.6MB) lives in the 256MB LLC, so the 256MB of RMW
// update traffic is cache-side; HBM sees only ~26MB writeback.
// Pipeline: memset(out) -> scatter_mul_atomic. 2 dispatches, no workspace.

typedef float vfloat4 __attribute__((ext_vector_type(4)));

// One wave per chunk of edges; lane owns feature `lane`. Per edge:
//  - dst/src: wave-uniform 4B loads (L1 broadcast)
//  - ea row:  64 lanes x 4B = 256B contiguous, streaming (NT)
//  - x row:   256B contiguous at random row (L2/LLC-resident, 25.6MB)
//  - out row: 256B contiguous atomicAdd (no return) at random row
// Unroll 4 -> 4 independent load->fma->atomic chains in flight per wave.
__global__ void scatter_mul_atomic(const float* __restrict__ x,
                                   const int* __restrict__ edge_index,
                                   const float* __restrict__ edge_attr,
                                   float* __restrict__ out,
                                   int E, int epw) {
    const int lane = threadIdx.x & 63;
    const int w = blockIdx.x * (blockDim.x >> 6) + (threadIdx.x >> 6);
    int e = w * epw;
    int e1 = e + epw;
    if (e1 > E) e1 = E;

    for (; e + 3 < e1; e += 4) {
        int d0 = edge_index[e],     d1 = edge_index[e + 1];
        int d2 = edge_index[e + 2], d3 = edge_index[e + 3];
        int s0 = edge_index[E + e],     s1 = edge_index[E + e + 1];
        int s2 = edge_index[E + e + 2], s3 = edge_index[E + e + 3];
        float a0 = __builtin_nontemporal_load(edge_attr + (size_t)e * 64 + lane);
        float a1 = __builtin_nontemporal_load(edge_attr + (size_t)(e + 1) * 64 + lane);
        float a2 = __builtin_nontemporal_load(edge_attr + (size_t)(e + 2) * 64 + lane);
        float a3 = __builtin_nontemporal_load(edge_attr + (size_t)(e + 3) * 64 + lane);
        float v0 = x[(size_t)s0 * 64 + lane];
        float v1 = x[(size_t)s1 * 64 + lane];
        float v2 = x[(size_t)s2 * 64 + lane];
        float v3 = x[(size_t)s3 * 64 + lane];
        atomicAdd(out + (size_t)d0 * 64 + lane, a0 * v0);
        atomicAdd(out + (size_t)d1 * 64 + lane, a1 * v1);
        atomicAdd(out + (size_t)d2 * 64 + lane, a2 * v2);
        atomicAdd(out + (size_t)d3 * 64 + lane, a3 * v3);
    }
    for (; e < e1; e++) {
        int d = edge_index[e], s = edge_index[E + e];
        float a = __builtin_nontemporal_load(edge_attr + (size_t)e * 64 + lane);
        atomicAdd(out + (size_t)d * 64 + lane, a * x[(size_t)s * 64 + lane]);
    }
}

extern "C" void kernel_launch(void* const* d_in, const int* in_sizes, int n_in,
                              void* d_out, int out_size, void* d_ws, size_t ws_size,
                              hipStream_t stream) {
    const float* x          = (const float*)d_in[0];
    const int*   edge_index = (const int*)d_in[1];
    const float* edge_attr  = (const float*)d_in[2];
    float*       out        = (float*)d_out;

    const int E = in_sizes[1] / 2;   // edge_index is [2, E]

    // out must start at zero: atomics accumulate into it.
    hipMemsetAsync(out, 0, (size_t)out_size * sizeof(float), stream);

    // 8192 waves = full residency at 32 waves/CU x 256 CU; each wave owns a
    // contiguous edge chunk so the edge_attr stream stays sequential per wave.
    const int block = 256;               // 4 waves/block
    const int grid = 2048;               // 8192 waves
    const int waves = grid * (block / 64);
    const int epw = (E + waves - 1) / waves;
    scatter_mul_atomic<<<grid, block, 0, stream>>>(x, edge_index, edge_attr,
                                                   out, E, epw);
}